// Round 2
// baseline (3695.239 us; speedup 1.0000x reference)
//
#include <hip/hip_runtime.h>

// Problem constants
#define RS 131072            // R*S = 4096*32
#define SPB 32               // samples per block (= S, one ray per block)
#define NBLK (RS / SPB)      // 4096 blocks

__device__ __forceinline__ float bf2f(unsigned short b) { return __uint_as_float(((unsigned)b) << 16); }
__device__ __forceinline__ unsigned short f2bf(float f) {
  unsigned u = __float_as_uint(f);
  return (unsigned short)((u + 0x7fffu + ((u >> 16) & 1u)) >> 16);  // RNE
}

__device__ __forceinline__ void macc4(float a, float4 q, float* acc) {
  acc[0] = fmaf(a, q.x, acc[0]);
  acc[1] = fmaf(a, q.y, acc[1]);
  acc[2] = fmaf(a, q.z, acc[2]);
  acc[3] = fmaf(a, q.w, acc[3]);
}

__global__ __launch_bounds__(256) void nerf_fused(
    const float* __restrict__ means,      // (R,S,M,3) f32
    const float* __restrict__ stds,       // (R,S,M)   f32
    const float* __restrict__ viewdirs,   // (R,3)     f32
    const float4* __restrict__ tab,       // table (TOTAL,4) f32 -> one float4/row
    const float4* __restrict__ W1, const float* __restrict__ b1,   // dw1 (40,64), db1(64)
    const float4* __restrict__ W2, const float* __restrict__ b2,   // dw2 (64,256), db2(256)
    const float4* __restrict__ W3, const float* __restrict__ b3,   // vw0 (283,256), vb0(256)
    const float4* __restrict__ W4, const float* __restrict__ b4,   // vw1 (539,256), vb1(256)
    const float* __restrict__ rw,  const float* __restrict__ rb,   // rw (256,3), rb(3)
    float* __restrict__ out)              // rgb (RS*3) then density (RS), f32
{
  __shared__ float sFeat[40][SPB];            //  5.0 KB
  __shared__ float sH[64][SPB];               //  8.0 KB
  __shared__ unsigned short sInp[283][SPB];   // 17.7 KB  (x[256] ++ dir_enc[27], bf16)
  __shared__ unsigned short sH2[256][SPB];    // 16.0 KB  (bf16)
  __shared__ float sRGB[24][SPB];             //  3.0 KB   => total ~49.7 KB

  const int tid = threadIdx.x;
  const int samp = tid & 31;
  const int g = tid >> 5;                 // worker group 0..7
  const int gsample = blockIdx.x * SPB + samp;

  // ---- viewdir positional encoding (one ray per block), rows 256..282 ----
  if (tid < SPB) {
    const int ray = blockIdx.x;
    float v0 = viewdirs[ray * 3 + 0];
    float v1 = viewdirs[ray * 3 + 1];
    float v2 = viewdirs[ray * 3 + 2];
    sInp[256][samp] = f2bf(v0);
    sInp[257][samp] = f2bf(v1);
    sInp[258][samp] = f2bf(v2);
    float v[3] = {v0, v1, v2};
    #pragma unroll
    for (int s = 0; s < 4; ++s) {
      float sc = (float)(1 << s);
      #pragma unroll
      for (int d = 0; d < 3; ++d) {
        float t = v[d] * sc;
        sInp[259 + s * 3 + d][samp] = f2bf(sinf(t));
        sInp[271 + s * 3 + d][samp] = f2bf(cosf(t));   // sin(t + pi/2)
      }
    }
  }

  // ---- hash-grid encode: worker g handles levels {g, g+8} for its sample ----
  for (int rep = 0; rep < 2; ++rep) {
    const int l = g + rep * 8;
    if (l >= 10) break;
    const float scale = (float)(16 << l);
    const bool dense = (l < 3);
    int off; unsigned szm1 = 0, Rr = 0;
    if (l == 0)      { off = 0;      szm1 = 4919;   Rr = 17; }   // 17^3=4913 -> 4920
    else if (l == 1) { off = 4920;   szm1 = 35943;  Rr = 33; }   // 33^3=35937 -> 35944
    else if (l == 2) { off = 40864;  szm1 = 274631; Rr = 65; }   // 65^3=274625 -> 274632
    else             { off = 315496 + (l - 3) * 2097152; }       // hashed, 2^21 each

    float a0 = 0.f, a1 = 0.f, a2 = 0.f, a3 = 0.f;
    for (int m = 0; m < 6; ++m) {
      const int pb = (gsample * 6 + m) * 3;
      float px = (means[pb + 0] + 1.f) * 0.5f * scale + 0.5f;
      float py = (means[pb + 1] + 1.f) * 0.5f * scale + 0.5f;
      float pz = (means[pb + 2] + 1.f) * 0.5f * scale + 0.5f;
      float f0 = floorf(px), f1 = floorf(py), f2c = floorf(pz);
      float fr0 = px - f0, fr1 = py - f1, fr2 = pz - f2c;
      unsigned c0 = (unsigned)f0, c1 = (unsigned)f1, c2 = (unsigned)f2c;
      float sd = stds[gsample * 6 + m];
      float wl = erff(1.f / sqrtf(8.f * sd * sd * scale * scale)) * (1.f / 6.f);
      #pragma unroll
      for (int c = 0; c < 8; ++c) {
        unsigned bx = c & 1u, by = (c >> 1) & 1u, bz = (c >> 2) & 1u;
        unsigned xx = c0 + bx, yy = c1 + by, zz = c2 + bz;
        unsigned idx;
        if (dense) {
          idx = (xx * Rr + yy) * Rr + zz;
          idx = (idx > szm1) ? szm1 : idx;          // JAX clip-mode gather
        } else {
          idx = (xx ^ (yy * 2654435761u) ^ (zz * 805459861u)) & 2097151u;
        }
        float w = (bx ? fr0 : 1.f - fr0) * (by ? fr1 : 1.f - fr1) * (bz ? fr2 : 1.f - fr2) * wl;
        float4 t = tab[(size_t)off + idx];
        a0 = fmaf(w, t.x, a0);
        a1 = fmaf(w, t.y, a1);
        a2 = fmaf(w, t.z, a2);
        a3 = fmaf(w, t.w, a3);
      }
    }
    sFeat[l * 4 + 0][samp] = a0;
    sFeat[l * 4 + 1][samp] = a1;
    sFeat[l * 4 + 2][samp] = a2;
    sFeat[l * 4 + 3][samp] = a3;
  }

  __syncthreads();

  // ---- L1: feat(40) @ dw1(40,64) + db1, relu ; group g -> outputs g*8..g*8+7 ----
  {
    float acc[8];
    #pragma unroll
    for (int j = 0; j < 8; ++j) acc[j] = 0.f;
    for (int i = 0; i < 40; ++i) {
      float a = sFeat[i][samp];
      float4 q0 = W1[i * 16 + g * 2 + 0];
      float4 q1 = W1[i * 16 + g * 2 + 1];
      macc4(a, q0, acc);
      macc4(a, q1, acc + 4);
    }
    #pragma unroll
    for (int j = 0; j < 8; ++j) {
      int o = g * 8 + j;
      sH[o][samp] = fmaxf(acc[j] + b1[o], 0.f);
    }
  }

  __syncthreads();

  // ---- L2: h(64) @ dw2(64,256) + db2 -> x ; density = softplus(x0 - 1) ----
  {
    float acc[32];
    #pragma unroll
    for (int j = 0; j < 32; ++j) acc[j] = 0.f;
    for (int i = 0; i < 64; ++i) {
      float a = sH[i][samp];
      #pragma unroll
      for (int k = 0; k < 8; ++k)
        macc4(a, W2[i * 64 + g * 8 + k], acc + k * 4);
    }
    #pragma unroll
    for (int j = 0; j < 32; ++j) {
      int o = g * 32 + j;
      float x = acc[j] + b2[o];
      sInp[o][samp] = f2bf(x);
      if (g == 0 && j == 0) {
        float t = x - 1.f;
        float den = fmaxf(t, 0.f) + log1pf(expf(-fabsf(t)));  // stable softplus
        out[RS * 3 + gsample] = den;
      }
    }
  }

  __syncthreads();

  // ---- L3: inp(283) @ vw0(283,256) + vb0, relu -> h2 ----
  {
    float acc[32];
    #pragma unroll
    for (int j = 0; j < 32; ++j) acc[j] = 0.f;
    for (int i = 0; i < 283; ++i) {
      float a = bf2f(sInp[i][samp]);
      #pragma unroll
      for (int k = 0; k < 8; ++k)
        macc4(a, W3[i * 64 + g * 8 + k], acc + k * 4);
    }
    #pragma unroll
    for (int j = 0; j < 32; ++j) {
      int o = g * 32 + j;
      sH2[o][samp] = f2bf(fmaxf(acc[j] + b3[o], 0.f));
    }
  }

  __syncthreads();

  // ---- L4: [h2(256); inp(283)] @ vw1(539,256) + vb1, relu ; fused rgb partials ----
  {
    float acc[32];
    #pragma unroll
    for (int j = 0; j < 32; ++j) acc[j] = 0.f;
    for (int i = 0; i < 256; ++i) {
      float a = bf2f(sH2[i][samp]);
      #pragma unroll
      for (int k = 0; k < 8; ++k)
        macc4(a, W4[i * 64 + g * 8 + k], acc + k * 4);
    }
    for (int i = 0; i < 283; ++i) {
      float a = bf2f(sInp[i][samp]);
      #pragma unroll
      for (int k = 0; k < 8; ++k)
        macc4(a, W4[(256 + i) * 64 + g * 8 + k], acc + k * 4);
    }
    float r0 = 0.f, r1 = 0.f, r2 = 0.f;
    #pragma unroll
    for (int j = 0; j < 32; ++j) {
      int o = g * 32 + j;
      float h3 = fmaxf(acc[j] + b4[o], 0.f);
      r0 = fmaf(h3, rw[o * 3 + 0], r0);
      r1 = fmaf(h3, rw[o * 3 + 1], r1);
      r2 = fmaf(h3, rw[o * 3 + 2], r2);
    }
    sRGB[g * 3 + 0][samp] = r0;
    sRGB[g * 3 + 1][samp] = r1;
    sRGB[g * 3 + 2][samp] = r2;
  }

  __syncthreads();

  // ---- reduce rgb partials over the 8 groups, sigmoid, store ----
  if (tid < 96) {
    int c = tid >> 5, sp = tid & 31;
    int gs = blockIdx.x * SPB + sp;
    float v = 0.f;
    #pragma unroll
    for (int k = 0; k < 8; ++k) v += sRGB[k * 3 + c][sp];
    v += rb[c];
    float sg = 1.f / (1.f + expf(-v));
    out[gs * 3 + c] = sg * 1.002f - 0.001f;
  }
}

extern "C" void kernel_launch(void* const* d_in, const int* in_sizes, int n_in,
                              void* d_out, int out_size, void* d_ws, size_t ws_size,
                              hipStream_t stream) {
  (void)in_sizes; (void)n_in; (void)d_ws; (void)ws_size; (void)out_size;
  nerf_fused<<<NBLK, 256, 0, stream>>>(
      (const float*)d_in[0],  (const float*)d_in[1],  (const float*)d_in[2],
      (const float4*)d_in[3],
      (const float4*)d_in[4], (const float*)d_in[5],
      (const float4*)d_in[6], (const float*)d_in[7],
      (const float4*)d_in[8], (const float*)d_in[9],
      (const float4*)d_in[10], (const float*)d_in[11],
      (const float*)d_in[12], (const float*)d_in[13],
      (float*)d_out);
}

// Round 3
// 949.023 us; speedup vs baseline: 3.8937x; 3.8937x over previous
//
#include <hip/hip_runtime.h>

// Problem constants
#define RS 131072            // R*S = 4096*32
#define SPB 32               // samples per block (= S, one ray per block)
#define NBLK (RS / SPB)      // 4096 blocks

// MFMA fragment types (gfx950: v8bf16 operands, v4f32 acc)
typedef __bf16 v8bf __attribute__((ext_vector_type(8)));
typedef float  v4f  __attribute__((ext_vector_type(4)));

// LDS row pads (bf16 elements): chosen so row_stride/16B is odd -> <=2-way bank alias (free)
#define KF 72     // feats / h rows   (144 B)
#define KX 296    // x++dir rows      (592 B)
#define KH 264    // h2 rows          (528 B)

// ws layout (ushort elements)
#define WS_FEATS   0
#define WS_W1T     (131072 * 72)                 // 9,437,184
#define WS_W2T     (WS_W1T + 64 * 64)            // + 4096
#define WS_W3T     (WS_W2T + 256 * 64)           // + 16384
#define WS_W4T     (WS_W3T + 256 * 288)          // + 73728
#define WS_DIR     (WS_W4T + 256 * 544)          // + 139264
#define WS_TOTAL   (WS_DIR + 4096 * 32)          // + 131072 = 9,801,728 ushort
#define WS_NEED_BYTES ((size_t)WS_TOTAL * 2)     // 19,603,456 B

__device__ __forceinline__ float bf2f(unsigned short b) { return __uint_as_float(((unsigned)b) << 16); }
__device__ __forceinline__ unsigned short f2bf(float f) {
  unsigned u = __float_as_uint(f);
  return (unsigned short)((u + 0x7fffu + ((u >> 16) & 1u)) >> 16);  // RNE
}

// ============================ K1: prep (weights -> bf16 transposed, dir enc) ============================
// jobs: W1t 4096 | W2t 16384 | W3t 73728 | W4t 139264 | direnc 131072  => 364544 = 1424*256
__global__ __launch_bounds__(256) void prep(
    const float* __restrict__ dw1, const float* __restrict__ dw2,
    const float* __restrict__ vw0, const float* __restrict__ vw1,
    const float* __restrict__ viewdirs,
    unsigned short* __restrict__ ws)
{
  int j = blockIdx.x * 256 + threadIdx.x;
  if (j < 4096) {                                   // W1t[64][64], K=40 padded
    int n = j >> 6, k = j & 63;
    float v = (k < 40) ? dw1[k * 64 + n] : 0.f;
    ws[WS_W1T + n * 64 + k] = f2bf(v);
  } else if (j < 20480) {                           // W2t[256][64], K=64 exact
    int i = j - 4096;
    int n = i >> 6, k = i & 63;
    ws[WS_W2T + n * 64 + k] = f2bf(dw2[k * 256 + n]);
  } else if (j < 94208) {                           // W3t[256][288], K=283 padded
    int i = j - 20480;
    int n = i / 288, k = i % 288;
    float v = (k < 283) ? vw0[k * 256 + n] : 0.f;
    ws[WS_W3T + n * 288 + k] = f2bf(v);
  } else if (j < 233472) {                          // W4t[256][544], K=539 padded
    int i = j - 94208;
    int n = i / 544, k = i % 544;
    float v = (k < 539) ? vw1[k * 256 + n] : 0.f;
    ws[WS_W4T + n * 544 + k] = f2bf(v);
  } else {                                          // direnc[4096][32]
    int i = j - 233472;
    int ray = i >> 5, c = i & 31;
    float val = 0.f;
    if (c < 27) {
      float v0 = viewdirs[ray * 3 + 0], v1 = viewdirs[ray * 3 + 1], v2 = viewdirs[ray * 3 + 2];
      float v[3] = {v0, v1, v2};
      if (c < 3) val = v[c];
      else if (c < 15) { int s = (c - 3) / 3, d = (c - 3) % 3; val = sinf(v[d] * (float)(1 << s)); }
      else             { int s = (c - 15) / 3, d = (c - 15) % 3; val = cosf(v[d] * (float)(1 << s)); }
    }
    ws[WS_DIR + ray * 32 + c] = f2bf(val);
  }
}

// ============================ K2: hash-grid encode ============================
// level-major: jobs [0, 10*131072): level = job>>17, sample = job&131071
// tail jobs zero-fill feat cols 40..71.  grid = 6144*256
__global__ __launch_bounds__(256) void encode(
    const float* __restrict__ means, const float* __restrict__ stds,
    const float4* __restrict__ tab,
    unsigned short* __restrict__ ws)
{
  unsigned job = blockIdx.x * 256 + threadIdx.x;
  unsigned short* feats = ws + WS_FEATS;
  if (job >= 10u * 131072u) {
    unsigned idx = job - 10u * 131072u;          // 0..262143
    unsigned sample = idx >> 1, half = idx & 1;
    uint4 z = {0, 0, 0, 0};
    *(uint4*)(feats + (size_t)sample * KF + 40 + half * 16) = z;
    return;
  }
  const unsigned level = job >> 17;
  const unsigned sample = job & 131071u;

  const float scale = (float)(16 << level);
  const bool dense = (level < 3);
  int off; unsigned szm1 = 0, Rr = 0;
  if (level == 0)      { off = 0;      szm1 = 4919;   Rr = 17; }
  else if (level == 1) { off = 4920;   szm1 = 35943;  Rr = 33; }
  else if (level == 2) { off = 40864;  szm1 = 274631; Rr = 65; }
  else                 { off = 315496 + (level - 3) * 2097152; }

  // preload all 6 sub-sample positions first (maximize outstanding gathers)
  unsigned c0[6], c1[6], c2[6];
  float fr0[6], fr1[6], fr2[6], wl[6];
  #pragma unroll
  for (int m = 0; m < 6; ++m) {
    const size_t pb = ((size_t)sample * 6 + m) * 3;
    float px = (means[pb + 0] + 1.f) * 0.5f * scale + 0.5f;
    float py = (means[pb + 1] + 1.f) * 0.5f * scale + 0.5f;
    float pz = (means[pb + 2] + 1.f) * 0.5f * scale + 0.5f;
    float f0 = floorf(px), f1 = floorf(py), f2c = floorf(pz);
    fr0[m] = px - f0; fr1[m] = py - f1; fr2[m] = pz - f2c;
    c0[m] = (unsigned)f0; c1[m] = (unsigned)f1; c2[m] = (unsigned)f2c;
    float sd = stds[(size_t)sample * 6 + m];
    wl[m] = erff(1.f / sqrtf(8.f * sd * sd * scale * scale)) * (1.f / 6.f);
  }

  float a0 = 0.f, a1 = 0.f, a2 = 0.f, a3 = 0.f;
  #pragma unroll 2
  for (int m = 0; m < 6; ++m) {
    #pragma unroll
    for (int c = 0; c < 8; ++c) {
      unsigned bx = c & 1u, by = (c >> 1) & 1u, bz = (c >> 2) & 1u;
      unsigned xx = c0[m] + bx, yy = c1[m] + by, zz = c2[m] + bz;
      unsigned idx;
      if (dense) {
        idx = (xx * Rr + yy) * Rr + zz;
        idx = (idx > szm1) ? szm1 : idx;          // JAX clip-mode gather
      } else {
        idx = (xx ^ (yy * 2654435761u) ^ (zz * 805459861u)) & 2097151u;
      }
      float w = (bx ? fr0[m] : 1.f - fr0[m]) * (by ? fr1[m] : 1.f - fr1[m]) * (bz ? fr2[m] : 1.f - fr2[m]) * wl[m];
      float4 t = tab[(size_t)off + idx];
      a0 = fmaf(w, t.x, a0);
      a1 = fmaf(w, t.y, a1);
      a2 = fmaf(w, t.z, a2);
      a3 = fmaf(w, t.w, a3);
    }
  }
  uint2 p;
  p.x = (unsigned)f2bf(a0) | ((unsigned)f2bf(a1) << 16);
  p.y = (unsigned)f2bf(a2) | ((unsigned)f2bf(a3) << 16);
  *(uint2*)(feats + (size_t)sample * KF + level * 4) = p;
}

// ============================ K3: fused MFMA MLP ============================
__global__ __launch_bounds__(256) void mlp(
    const unsigned short* __restrict__ ws,
    const float* __restrict__ b1, const float* __restrict__ b2,
    const float* __restrict__ b3, const float* __restrict__ b4,
    const float* __restrict__ rw, const float* __restrict__ rb,
    float* __restrict__ out)
{
  __shared__ __align__(16) unsigned short sF[32 * KF];    // feats, A for L1
  __shared__ __align__(16) unsigned short sHa[32 * KF];   // h, A for L2
  __shared__ __align__(16) unsigned short sX[32 * KX];    // x ++ dir, A for L3 & L4-tail
  __shared__ __align__(16) unsigned short sH2[32 * KH];   // h2, A for L4-head
  __shared__ __align__(16) unsigned short sDir[32];
  __shared__ float sR[4][32][3];

  const unsigned short* feats_g = ws + WS_FEATS;
  const unsigned short* W1t = ws + WS_W1T;
  const unsigned short* W2t = ws + WS_W2T;
  const unsigned short* W3t = ws + WS_W3T;
  const unsigned short* W4t = ws + WS_W4T;
  const unsigned short* dir_g = ws + WS_DIR;

  const int tid = threadIdx.x;
  const int ray = blockIdx.x;
  const int lane = tid & 63;
  const int q = tid >> 6;          // wave id = N-quarter
  const int col = lane & 15;
  const int quad = lane >> 4;
  const int q8 = quad * 8;

  // ---- stage feats (288 x 16B) + dir (64 B) ----
  {
    const uint4* src = (const uint4*)(feats_g + (size_t)ray * 32 * KF);
    uint4* dst = (uint4*)sF;
    dst[tid] = src[tid];
    if (tid < 32) dst[256 + tid] = src[256 + tid];
    if (tid < 4) ((uint4*)sDir)[tid] = ((const uint4*)(dir_g + ray * 32))[tid];
  }
  __syncthreads();

  // ---- fill sX rows (cols 256..287): dir enc broadcast (zeros baked in >=27) ----
  {
    int samp = tid & 31, kk = tid >> 5;       // kk 0..7 -> cols 256+kk*4 .. +3
    unsigned v0 = (unsigned)sDir[kk * 4 + 0] | ((unsigned)sDir[kk * 4 + 1] << 16);
    unsigned v1 = (unsigned)sDir[kk * 4 + 2] | ((unsigned)sDir[kk * 4 + 3] << 16);
    uint2 p; p.x = v0; p.y = v1;
    *(uint2*)(sX + samp * KX + 256 + kk * 4) = p;
  }

  // ---- L1: feat(64K) @ W1t -> h(64).  wave q: n-tile q*16, M-tiles 0,1 ----
  v4f acc[2][4];
  #pragma unroll
  for (int a = 0; a < 2; ++a) acc[a][0] = (v4f){0.f, 0.f, 0.f, 0.f};
  #pragma unroll
  for (int stp = 0; stp < 2; ++stp) {
    const int k0 = stp * 32;
    v8bf a0 = *(const v8bf*)(sF + (col) * KF + k0 + q8);
    v8bf a1 = *(const v8bf*)(sF + (col + 16) * KF + k0 + q8);
    v8bf b = *(const v8bf*)(W1t + (size_t)(q * 16 + col) * 64 + k0 + q8);
    acc[0][0] = __builtin_amdgcn_mfma_f32_16x16x32_bf16(a0, b, acc[0][0], 0, 0, 0);
    acc[1][0] = __builtin_amdgcn_mfma_f32_16x16x32_bf16(a1, b, acc[1][0], 0, 0, 0);
  }
  {
    float bb = b1[q * 16 + col];
    #pragma unroll
    for (int Mt = 0; Mt < 2; ++Mt)
      #pragma unroll
      for (int r = 0; r < 4; ++r) {
        int s = Mt * 16 + quad * 4 + r;
        sHa[s * KF + q * 16 + col] = f2bf(fmaxf(acc[Mt][0][r] + bb, 0.f));
      }
  }
  __syncthreads();

  // ---- L2: h(64K) @ W2t -> x(256). wave q: n-tiles q*64+j*16 ----
  #pragma unroll
  for (int a = 0; a < 2; ++a)
    #pragma unroll
    for (int b_ = 0; b_ < 4; ++b_) acc[a][b_] = (v4f){0.f, 0.f, 0.f, 0.f};
  #pragma unroll
  for (int stp = 0; stp < 2; ++stp) {
    const int k0 = stp * 32;
    v8bf a0 = *(const v8bf*)(sHa + (col) * KF + k0 + q8);
    v8bf a1 = *(const v8bf*)(sHa + (col + 16) * KF + k0 + q8);
    #pragma unroll
    for (int j = 0; j < 4; ++j) {
      v8bf b = *(const v8bf*)(W2t + (size_t)(q * 64 + j * 16 + col) * 64 + k0 + q8);
      acc[0][j] = __builtin_amdgcn_mfma_f32_16x16x32_bf16(a0, b, acc[0][j], 0, 0, 0);
      acc[1][j] = __builtin_amdgcn_mfma_f32_16x16x32_bf16(a1, b, acc[1][j], 0, 0, 0);
    }
  }
  #pragma unroll
  for (int j = 0; j < 4; ++j) {
    int n = q * 64 + j * 16 + col;
    float bb = b2[n];
    #pragma unroll
    for (int Mt = 0; Mt < 2; ++Mt)
      #pragma unroll
      for (int r = 0; r < 4; ++r) {
        int s = Mt * 16 + quad * 4 + r;
        float x = acc[Mt][j][r] + bb;
        sX[s * KX + n] = f2bf(x);
        if (n == 0) {  // density (f32 path)
          float t = x - 1.f;
          out[RS * 3 + ray * 32 + s] = fmaxf(t, 0.f) + log1pf(expf(-fabsf(t)));
        }
      }
  }
  __syncthreads();

  // ---- L3: inp(288K from sX) @ W3t -> h2(256) ----
  #pragma unroll
  for (int a = 0; a < 2; ++a)
    #pragma unroll
    for (int b_ = 0; b_ < 4; ++b_) acc[a][b_] = (v4f){0.f, 0.f, 0.f, 0.f};
  #pragma unroll
  for (int stp = 0; stp < 9; ++stp) {
    const int k0 = stp * 32;
    v8bf a0 = *(const v8bf*)(sX + (col) * KX + k0 + q8);
    v8bf a1 = *(const v8bf*)(sX + (col + 16) * KX + k0 + q8);
    #pragma unroll
    for (int j = 0; j < 4; ++j) {
      v8bf b = *(const v8bf*)(W3t + (size_t)(q * 64 + j * 16 + col) * 288 + k0 + q8);
      acc[0][j] = __builtin_amdgcn_mfma_f32_16x16x32_bf16(a0, b, acc[0][j], 0, 0, 0);
      acc[1][j] = __builtin_amdgcn_mfma_f32_16x16x32_bf16(a1, b, acc[1][j], 0, 0, 0);
    }
  }
  #pragma unroll
  for (int j = 0; j < 4; ++j) {
    int n = q * 64 + j * 16 + col;
    float bb = b3[n];
    #pragma unroll
    for (int Mt = 0; Mt < 2; ++Mt)
      #pragma unroll
      for (int r = 0; r < 4; ++r) {
        int s = Mt * 16 + quad * 4 + r;
        sH2[s * KH + n] = f2bf(fmaxf(acc[Mt][j][r] + bb, 0.f));
      }
  }
  __syncthreads();

  // ---- L4: [h2(256); inp(288)] @ W4t -> h3(256), fused rgb head ----
  #pragma unroll
  for (int a = 0; a < 2; ++a)
    #pragma unroll
    for (int b_ = 0; b_ < 4; ++b_) acc[a][b_] = (v4f){0.f, 0.f, 0.f, 0.f};
  #pragma unroll
  for (int stp = 0; stp < 8; ++stp) {          // k 0..255 from h2
    const int k0 = stp * 32;
    v8bf a0 = *(const v8bf*)(sH2 + (col) * KH + k0 + q8);
    v8bf a1 = *(const v8bf*)(sH2 + (col + 16) * KH + k0 + q8);
    #pragma unroll
    for (int j = 0; j < 4; ++j) {
      v8bf b = *(const v8bf*)(W4t + (size_t)(q * 64 + j * 16 + col) * 544 + k0 + q8);
      acc[0][j] = __builtin_amdgcn_mfma_f32_16x16x32_bf16(a0, b, acc[0][j], 0, 0, 0);
      acc[1][j] = __builtin_amdgcn_mfma_f32_16x16x32_bf16(a1, b, acc[1][j], 0, 0, 0);
    }
  }
  #pragma unroll
  for (int stp = 8; stp < 17; ++stp) {         // k 256..543 from inp (sX)
    const int k0l = (stp - 8) * 32;
    const int k0g = stp * 32;
    v8bf a0 = *(const v8bf*)(sX + (col) * KX + k0l + q8);
    v8bf a1 = *(const v8bf*)(sX + (col + 16) * KX + k0l + q8);
    #pragma unroll
    for (int j = 0; j < 4; ++j) {
      v8bf b = *(const v8bf*)(W4t + (size_t)(q * 64 + j * 16 + col) * 544 + k0g + q8);
      acc[0][j] = __builtin_amdgcn_mfma_f32_16x16x32_bf16(a0, b, acc[0][j], 0, 0, 0);
      acc[1][j] = __builtin_amdgcn_mfma_f32_16x16x32_bf16(a1, b, acc[1][j], 0, 0, 0);
    }
  }
  // rgb head: per-lane partials over (j), reduce over col lanes, then waves
  {
    float racc[2][4][3];
    #pragma unroll
    for (int Mt = 0; Mt < 2; ++Mt)
      #pragma unroll
      for (int r = 0; r < 4; ++r)
        #pragma unroll
        for (int c = 0; c < 3; ++c) racc[Mt][r][c] = 0.f;
    #pragma unroll
    for (int j = 0; j < 4; ++j) {
      int n = q * 64 + j * 16 + col;
      float bb = b4[n];
      float w0 = rw[n * 3 + 0], w1 = rw[n * 3 + 1], w2 = rw[n * 3 + 2];
      #pragma unroll
      for (int Mt = 0; Mt < 2; ++Mt)
        #pragma unroll
        for (int r = 0; r < 4; ++r) {
          float h3 = fmaxf(acc[Mt][j][r] + bb, 0.f);
          racc[Mt][r][0] = fmaf(h3, w0, racc[Mt][r][0]);
          racc[Mt][r][1] = fmaf(h3, w1, racc[Mt][r][1]);
          racc[Mt][r][2] = fmaf(h3, w2, racc[Mt][r][2]);
        }
    }
    #pragma unroll
    for (int m = 1; m < 16; m <<= 1)
      #pragma unroll
      for (int Mt = 0; Mt < 2; ++Mt)
        #pragma unroll
        for (int r = 0; r < 4; ++r)
          #pragma unroll
          for (int c = 0; c < 3; ++c)
            racc[Mt][r][c] += __shfl_xor(racc[Mt][r][c], m, 64);
    if (col == 0) {
      #pragma unroll
      for (int Mt = 0; Mt < 2; ++Mt)
        #pragma unroll
        for (int r = 0; r < 4; ++r) {
          int s = Mt * 16 + quad * 4 + r;
          #pragma unroll
          for (int c = 0; c < 3; ++c) sR[q][s][c] = racc[Mt][r][c];
        }
    }
  }
  __syncthreads();

  if (tid < 96) {
    int c = tid >> 5, samp = tid & 31;
    float v = sR[0][samp][c] + sR[1][samp][c] + sR[2][samp][c] + sR[3][samp][c] + rb[c];
    float sg = 1.f / (1.f + expf(-v));
    out[((size_t)ray * 32 + samp) * 3 + c] = sg * 1.002f - 0.001f;
  }
}

// ============================ Fallback: round-2 fused kernel ============================
__device__ __forceinline__ void macc4(float a, float4 qd, float* a_) {
  a_[0] = fmaf(a, qd.x, a_[0]); a_[1] = fmaf(a, qd.y, a_[1]);
  a_[2] = fmaf(a, qd.z, a_[2]); a_[3] = fmaf(a, qd.w, a_[3]);
}

__global__ __launch_bounds__(256) void nerf_fused(
    const float* __restrict__ means, const float* __restrict__ stds,
    const float* __restrict__ viewdirs, const float4* __restrict__ tab,
    const float4* __restrict__ W1, const float* __restrict__ b1,
    const float4* __restrict__ W2, const float* __restrict__ b2,
    const float4* __restrict__ W3, const float* __restrict__ b3,
    const float4* __restrict__ W4, const float* __restrict__ b4,
    const float* __restrict__ rw,  const float* __restrict__ rb,
    float* __restrict__ out)
{
  __shared__ float sFeat[40][SPB];
  __shared__ float sH[64][SPB];
  __shared__ unsigned short sInp[283][SPB];
  __shared__ unsigned short sH2[256][SPB];
  __shared__ float sRGB[24][SPB];

  const int tid = threadIdx.x;
  const int samp = tid & 31;
  const int g = tid >> 5;
  const int gsample = blockIdx.x * SPB + samp;

  if (tid < SPB) {
    const int ray = blockIdx.x;
    float v0 = viewdirs[ray * 3 + 0], v1 = viewdirs[ray * 3 + 1], v2 = viewdirs[ray * 3 + 2];
    sInp[256][samp] = f2bf(v0); sInp[257][samp] = f2bf(v1); sInp[258][samp] = f2bf(v2);
    float v[3] = {v0, v1, v2};
    #pragma unroll
    for (int s = 0; s < 4; ++s) {
      float sc = (float)(1 << s);
      #pragma unroll
      for (int d = 0; d < 3; ++d) {
        float t = v[d] * sc;
        sInp[259 + s * 3 + d][samp] = f2bf(sinf(t));
        sInp[271 + s * 3 + d][samp] = f2bf(cosf(t));
      }
    }
  }
  for (int rep = 0; rep < 2; ++rep) {
    const int l = g + rep * 8;
    if (l >= 10) break;
    const float scale = (float)(16 << l);
    const bool dense = (l < 3);
    int off; unsigned szm1 = 0, Rr = 0;
    if (l == 0)      { off = 0;      szm1 = 4919;   Rr = 17; }
    else if (l == 1) { off = 4920;   szm1 = 35943;  Rr = 33; }
    else if (l == 2) { off = 40864;  szm1 = 274631; Rr = 65; }
    else             { off = 315496 + (l - 3) * 2097152; }
    float a0 = 0.f, a1 = 0.f, a2 = 0.f, a3 = 0.f;
    for (int m = 0; m < 6; ++m) {
      const int pb = (gsample * 6 + m) * 3;
      float px = (means[pb + 0] + 1.f) * 0.5f * scale + 0.5f;
      float py = (means[pb + 1] + 1.f) * 0.5f * scale + 0.5f;
      float pz = (means[pb + 2] + 1.f) * 0.5f * scale + 0.5f;
      float f0 = floorf(px), f1 = floorf(py), f2c = floorf(pz);
      float fr0 = px - f0, fr1 = py - f1, fr2 = pz - f2c;
      unsigned c0 = (unsigned)f0, c1 = (unsigned)f1, c2 = (unsigned)f2c;
      float sd = stds[gsample * 6 + m];
      float wl = erff(1.f / sqrtf(8.f * sd * sd * scale * scale)) * (1.f / 6.f);
      #pragma unroll
      for (int c = 0; c < 8; ++c) {
        unsigned bx = c & 1u, by = (c >> 1) & 1u, bz = (c >> 2) & 1u;
        unsigned xx = c0 + bx, yy = c1 + by, zz = c2 + bz;
        unsigned idx;
        if (dense) { idx = (xx * Rr + yy) * Rr + zz; idx = (idx > szm1) ? szm1 : idx; }
        else { idx = (xx ^ (yy * 2654435761u) ^ (zz * 805459861u)) & 2097151u; }
        float w = (bx ? fr0 : 1.f - fr0) * (by ? fr1 : 1.f - fr1) * (bz ? fr2 : 1.f - fr2) * wl;
        float4 t = tab[(size_t)off + idx];
        a0 = fmaf(w, t.x, a0); a1 = fmaf(w, t.y, a1); a2 = fmaf(w, t.z, a2); a3 = fmaf(w, t.w, a3);
      }
    }
    sFeat[l * 4 + 0][samp] = a0; sFeat[l * 4 + 1][samp] = a1;
    sFeat[l * 4 + 2][samp] = a2; sFeat[l * 4 + 3][samp] = a3;
  }
  __syncthreads();
  {
    float a_[8];
    #pragma unroll
    for (int j = 0; j < 8; ++j) a_[j] = 0.f;
    for (int i = 0; i < 40; ++i) {
      float a = sFeat[i][samp];
      macc4(a, W1[i * 16 + g * 2 + 0], a_); macc4(a, W1[i * 16 + g * 2 + 1], a_ + 4);
    }
    #pragma unroll
    for (int j = 0; j < 8; ++j) { int o = g * 8 + j; sH[o][samp] = fmaxf(a_[j] + b1[o], 0.f); }
  }
  __syncthreads();
  {
    float a_[32];
    #pragma unroll
    for (int j = 0; j < 32; ++j) a_[j] = 0.f;
    for (int i = 0; i < 64; ++i) {
      float a = sH[i][samp];
      #pragma unroll
      for (int k = 0; k < 8; ++k) macc4(a, W2[i * 64 + g * 8 + k], a_ + k * 4);
    }
    #pragma unroll
    for (int j = 0; j < 32; ++j) {
      int o = g * 32 + j;
      float x = a_[j] + b2[o];
      sInp[o][samp] = f2bf(x);
      if (g == 0 && j == 0) {
        float t = x - 1.f;
        out[RS * 3 + gsample] = fmaxf(t, 0.f) + log1pf(expf(-fabsf(t)));
      }
    }
  }
  __syncthreads();
  {
    float a_[32];
    #pragma unroll
    for (int j = 0; j < 32; ++j) a_[j] = 0.f;
    for (int i = 0; i < 283; ++i) {
      float a = bf2f(sInp[i][samp]);
      #pragma unroll
      for (int k = 0; k < 8; ++k) macc4(a, W3[i * 64 + g * 8 + k], a_ + k * 4);
    }
    #pragma unroll
    for (int j = 0; j < 32; ++j) { int o = g * 32 + j; sH2[o][samp] = f2bf(fmaxf(a_[j] + b3[o], 0.f)); }
  }
  __syncthreads();
  {
    float a_[32];
    #pragma unroll
    for (int j = 0; j < 32; ++j) a_[j] = 0.f;
    for (int i = 0; i < 256; ++i) {
      float a = bf2f(sH2[i][samp]);
      #pragma unroll
      for (int k = 0; k < 8; ++k) macc4(a, W4[i * 64 + g * 8 + k], a_ + k * 4);
    }
    for (int i = 0; i < 283; ++i) {
      float a = bf2f(sInp[i][samp]);
      #pragma unroll
      for (int k = 0; k < 8; ++k) macc4(a, W4[(256 + i) * 64 + g * 8 + k], a_ + k * 4);
    }
    float r0 = 0.f, r1 = 0.f, r2 = 0.f;
    #pragma unroll
    for (int j = 0; j < 32; ++j) {
      int o = g * 32 + j;
      float h3 = fmaxf(a_[j] + b4[o], 0.f);
      r0 = fmaf(h3, rw[o * 3 + 0], r0); r1 = fmaf(h3, rw[o * 3 + 1], r1); r2 = fmaf(h3, rw[o * 3 + 2], r2);
    }
    sRGB[g * 3 + 0][samp] = r0; sRGB[g * 3 + 1][samp] = r1; sRGB[g * 3 + 2][samp] = r2;
  }
  __syncthreads();
  if (tid < 96) {
    int c = tid >> 5, sp = tid & 31;
    int gs = blockIdx.x * SPB + sp;
    float v = 0.f;
    #pragma unroll
    for (int k = 0; k < 8; ++k) v += sRGB[k * 3 + c][sp];
    v += rb[c];
    float sg = 1.f / (1.f + expf(-v));
    out[gs * 3 + c] = sg * 1.002f - 0.001f;
  }
}

extern "C" void kernel_launch(void* const* d_in, const int* in_sizes, int n_in,
                              void* d_out, int out_size, void* d_ws, size_t ws_size,
                              hipStream_t stream) {
  (void)in_sizes; (void)n_in; (void)out_size;
  if (ws_size >= WS_NEED_BYTES) {
    unsigned short* ws = (unsigned short*)d_ws;
    prep<<<1424, 256, 0, stream>>>(
        (const float*)d_in[4], (const float*)d_in[6], (const float*)d_in[8],
        (const float*)d_in[10], (const float*)d_in[2], ws);
    encode<<<6144, 256, 0, stream>>>(
        (const float*)d_in[0], (const float*)d_in[1], (const float4*)d_in[3], ws);
    mlp<<<NBLK, 256, 0, stream>>>(
        ws,
        (const float*)d_in[5], (const float*)d_in[7], (const float*)d_in[9],
        (const float*)d_in[11], (const float*)d_in[12], (const float*)d_in[13],
        (float*)d_out);
  } else {
    nerf_fused<<<NBLK, 256, 0, stream>>>(
        (const float*)d_in[0],  (const float*)d_in[1],  (const float*)d_in[2],
        (const float4*)d_in[3],
        (const float4*)d_in[4], (const float*)d_in[5],
        (const float4*)d_in[6], (const float*)d_in[7],
        (const float4*)d_in[8], (const float*)d_in[9],
        (const float4*)d_in[10], (const float*)d_in[11],
        (const float*)d_in[12], (const float*)d_in[13],
        (float*)d_out);
  }
}